// Round 14
// baseline (255.379 us; speedup 1.0000x reference)
//
#include <hip/hip_runtime.h>
#include <hip/hip_bf16.h>

// EdgeConv, CSR-by-dst, bf16 intermediates:
//   abf[n] = bf16(h@W1[0:64]); bsf[n] = bf16(h@W1[64:128]+b1)
//   acc[n] = sum_{e:dst=n} relu(abf[src] + bsf[n] + e*w128)   (wave/node, lane=feat)
//   out[n] = acc[n] @ W2 + cnt[n]*b2                          (fused readlane matvec)
// R14: precompute role rebuilt SPILL-PROOF: max 16 named scalar weights live
//   (k-chunked), 4 nodes/wave, h via one coalesced float4/lane + readlane
//   broadcast. Evidence across R4/R6/R8/R11/R12/R13: arrays of 4-8 stay
//   resident; 64/128 get spill-wrapped regardless of pins/bounds (R12's
//   wreg[64]: VGPR=48, 55MB scratch). W1 chunks reloaded per wave (L1-hot
//   broadcast) - trading cheap VMEM issue for guaranteed residency.
//   Chain order identical to R12 (k ascending, xyzw inner) -> bitwise-same.
// node_accum: R3 byte-for-byte (88.2-88.5us x4; 5 epilogue attempts all lost).
// pipeline: count fused in pre dispatch (R10) -> single-cursor alloc ->
//   non-atomic fill (rank from count's atomicAdd).

#define NPB 16        // pre_count: nodes per block (4 waves x 4 nodes)

typedef unsigned int u32;

#define RL(v_, sl_) __uint_as_float(__builtin_amdgcn_readlane(__float_as_uint(v_), (sl_)))

#define SLICE4(sl_, wa_, wb_, wc_, wd_, ACC_) do {      \
    ACC_ = fmaf(RL(cur.x, (sl_)), wa_, ACC_);           \
    ACC_ = fmaf(RL(cur.y, (sl_)), wb_, ACC_);           \
    ACC_ = fmaf(RL(cur.z, (sl_)), wc_, ACC_);           \
    ACC_ = fmaf(RL(cur.w, (sl_)), wd_, ACC_);           \
} while (0)

#define CNODE(nn_, kc_, ACC_) do {                                   \
    SLICE4((nn_)*16 + 4*(kc_) + 0, w0,  w1,  w2,  w3,  ACC_);        \
    SLICE4((nn_)*16 + 4*(kc_) + 1, w4,  w5,  w6,  w7,  ACC_);        \
    SLICE4((nn_)*16 + 4*(kc_) + 2, w8,  w9,  w10, w11, ACC_);        \
    SLICE4((nn_)*16 + 4*(kc_) + 3, w12, w13, w14, w15, ACC_);        \
} while (0)

// one 16-row weight chunk (16 named scalars, statically indexed -> registers)
#define CHUNK(kc_, A0_, A1_, A2_, A3_) do {                                          \
    const float w0  = Wp[(size_t)(16*(kc_)+ 0)*64], w1  = Wp[(size_t)(16*(kc_)+ 1)*64], \
                w2  = Wp[(size_t)(16*(kc_)+ 2)*64], w3  = Wp[(size_t)(16*(kc_)+ 3)*64], \
                w4  = Wp[(size_t)(16*(kc_)+ 4)*64], w5  = Wp[(size_t)(16*(kc_)+ 5)*64], \
                w6  = Wp[(size_t)(16*(kc_)+ 6)*64], w7  = Wp[(size_t)(16*(kc_)+ 7)*64], \
                w8  = Wp[(size_t)(16*(kc_)+ 8)*64], w9  = Wp[(size_t)(16*(kc_)+ 9)*64], \
                w10 = Wp[(size_t)(16*(kc_)+10)*64], w11 = Wp[(size_t)(16*(kc_)+11)*64], \
                w12 = Wp[(size_t)(16*(kc_)+12)*64], w13 = Wp[(size_t)(16*(kc_)+13)*64], \
                w14 = Wp[(size_t)(16*(kc_)+14)*64], w15 = Wp[(size_t)(16*(kc_)+15)*64]; \
    CNODE(0, kc_, A0_); CNODE(1, kc_, A1_); CNODE(2, kc_, A2_); CNODE(3, kc_, A3_);  \
} while (0)

// ---------------- offset allocation, single global cursor ----------------
__global__ __launch_bounds__(256) void alloc_offs_kernel(const int* __restrict__ counts,
                                                         int* __restrict__ gcursor,
                                                         int* __restrict__ offs, int n) {
    __shared__ int wsum[4];
    const int i    = blockIdx.x * 256 + threadIdx.x;
    const int lane = threadIdx.x & 63;
    const int wv   = threadIdx.x >> 6;

    const int c = (i < n) ? counts[i] : 0;
    int incl = c;
    #pragma unroll
    for (int d = 1; d < 64; d <<= 1) {
        int v = __shfl_up(incl, d, 64);
        if (lane >= d) incl += v;
    }
    const int excl = incl - c;
    if (lane == 63) wsum[wv] = incl;
    __syncthreads();
    if (threadIdx.x == 0) {
        const int s0 = wsum[0], s1 = wsum[1], s2 = wsum[2], s3 = wsum[3];
        const int b = atomicAdd(gcursor, s0 + s1 + s2 + s3);
        wsum[0] = b; wsum[1] = b + s0; wsum[2] = b + s0 + s1; wsum[3] = b + s0 + s1 + s2;
    }
    __syncthreads();
    if (i < n) offs[i] = wsum[wv] + excl;
}

// ---------------- single-pass non-atomic fill ----------------
__global__ void fill_kernel(const int* __restrict__ dst, const int* __restrict__ src,
                            const float* __restrict__ e,
                            const int* __restrict__ offs, const int* __restrict__ rank,
                            int2* __restrict__ meta, int n_edges) {
    const int i = blockIdx.x * blockDim.x + threadIdx.x;
    if (i >= n_edges) return;
    const int d = dst[i];
    meta[offs[d] + rank[i]] = make_int2(src[i], __float_as_int(e[i]));
}

// ---------------- fused: precompute (blocks < pg) + count/rank (blocks >= pg) ----------------
// precompute: lane = output feature j; 4 nodes/wave; weights streamed in 16-reg
//   named-scalar chunks (spill-proof); h broadcast via readlane. No LDS.
// count role: rank[i] = atomicAdd(&counts[dst[i]], 1) — hides under precompute.
__global__ __launch_bounds__(256, 2) void pre_count_kernel(
    const float* __restrict__ h, const float* __restrict__ W1, const float* __restrict__ b1,
    unsigned short* __restrict__ abf, unsigned short* __restrict__ bsf, int n_nodes,
    const int* __restrict__ dst, int* __restrict__ counts, int* __restrict__ rank,
    int n_edges, int pg)
{
    const int lane = threadIdx.x & 63;
    const int wv   = threadIdx.x >> 6;

    if ((int)blockIdx.x >= pg) {
        // ---- count role ----
        const int i = ((int)blockIdx.x - pg) * 256 + threadIdx.x;
        if (i < n_edges) rank[i] = atomicAdd(&counts[dst[i]], 1);
        return;
    }

    // ---- precompute role: wave's 4 nodes ----
    const int nbase = (blockIdx.x * 4 + wv) * 4;
    if (nbase >= n_nodes) return;

    // one coalesced float4/lane covers rows nbase..nbase+3 (row = lane>>4, k4 = lane&15)
    float4 cur = make_float4(0.f, 0.f, 0.f, 0.f);
    {
        const int row = nbase + (lane >> 4);
        if (row < n_nodes)
            cur = reinterpret_cast<const float4*>(h)[(size_t)nbase * 16 + lane];
    }

    // ---- pass A: av over W1[0:64] -> abf ----
    {
        const float* __restrict__ Wp = W1 + lane;
        float av0 = 0.f, av1 = 0.f, av2 = 0.f, av3 = 0.f;
        CHUNK(0, av0, av1, av2, av3);
        CHUNK(1, av0, av1, av2, av3);
        CHUNK(2, av0, av1, av2, av3);
        CHUNK(3, av0, av1, av2, av3);
        __hip_bfloat16 r0 = __float2bfloat16(av0);
        __hip_bfloat16 r1 = __float2bfloat16(av1);
        __hip_bfloat16 r2 = __float2bfloat16(av2);
        __hip_bfloat16 r3 = __float2bfloat16(av3);
        if (nbase + 0 < n_nodes) abf[(size_t)(nbase + 0) * 64 + lane] = *reinterpret_cast<unsigned short*>(&r0);
        if (nbase + 1 < n_nodes) abf[(size_t)(nbase + 1) * 64 + lane] = *reinterpret_cast<unsigned short*>(&r1);
        if (nbase + 2 < n_nodes) abf[(size_t)(nbase + 2) * 64 + lane] = *reinterpret_cast<unsigned short*>(&r2);
        if (nbase + 3 < n_nodes) abf[(size_t)(nbase + 3) * 64 + lane] = *reinterpret_cast<unsigned short*>(&r3);
    }

    // ---- pass B: bv over W1[64:128] + b1 -> bsf ----
    {
        const float* __restrict__ Wp = W1 + (size_t)64 * 64 + lane;
        const float b1l = b1[lane];
        float bv0 = b1l, bv1 = b1l, bv2 = b1l, bv3 = b1l;
        CHUNK(0, bv0, bv1, bv2, bv3);
        CHUNK(1, bv0, bv1, bv2, bv3);
        CHUNK(2, bv0, bv1, bv2, bv3);
        CHUNK(3, bv0, bv1, bv2, bv3);
        __hip_bfloat16 r0 = __float2bfloat16(bv0);
        __hip_bfloat16 r1 = __float2bfloat16(bv1);
        __hip_bfloat16 r2 = __float2bfloat16(bv2);
        __hip_bfloat16 r3 = __float2bfloat16(bv3);
        if (nbase + 0 < n_nodes) bsf[(size_t)(nbase + 0) * 64 + lane] = *reinterpret_cast<unsigned short*>(&r0);
        if (nbase + 1 < n_nodes) bsf[(size_t)(nbase + 1) * 64 + lane] = *reinterpret_cast<unsigned short*>(&r1);
        if (nbase + 2 < n_nodes) bsf[(size_t)(nbase + 2) * 64 + lane] = *reinterpret_cast<unsigned short*>(&r2);
        if (nbase + 3 < n_nodes) bsf[(size_t)(nbase + 3) * 64 + lane] = *reinterpret_cast<unsigned short*>(&r3);
    }
}

// ---------------- accum: wave/node, lane=feat, register-meta + depth-8 prefetch ----------------
// (R3 exactly — proven 88.2-88.5us x4)
__global__ __launch_bounds__(256) void node_accum_kernel(
    const unsigned short* __restrict__ abf, const unsigned short* __restrict__ bsf,
    const float* __restrict__ W1, const float* __restrict__ W2, const float* __restrict__ b2,
    const int* __restrict__ offs, const int* __restrict__ counts,
    const int2* __restrict__ meta, float* __restrict__ out, int n_nodes)
{
    const int lane = threadIdx.x & 63;
    const int wv   = __builtin_amdgcn_readfirstlane(threadIdx.x >> 6);
    const int n    = blockIdx.x * 4 + wv;          // wave-uniform node id
    if (n >= n_nodes) return;

    const float basel = __uint_as_float((uint)bsf[(size_t)n * 64 + lane] << 16);
    const float w128l = W1[(size_t)128 * 64 + lane];
    float acc = 0.f;

    const int beg = offs[n];     // s_load (n uniform)
    const int np  = counts[n];   // s_load

    // chunks of <=64 edges: meta staged into registers by ONE lane-parallel load,
    // per-edge src/e extracted with v_readlane (no memory on the gather-addr path)
    for (int c0 = 0; c0 < np; c0 += 64) {
        const int cn = min(np - c0, 64);

        int mx = 0, my = 0;
        if (lane < cn) {
            const int2 m = meta[beg + c0 + lane];   // 512B coalesced, once per chunk
            mx = m.x; my = m.y;
        }

        // pipeline slots hold the RAW zext ushort; <<16 happens at consume time
        uint x0=0,x1=0,x2=0,x3=0,x4=0,x5=0,x6=0,x7=0;

        auto ld = [&](int j, uint& x) {
            const int s = __builtin_amdgcn_readlane(mx, j);        // uniform src id
            x = (uint)abf[(size_t)s * 64 + lane];                  // saddr gather, 128B/wave
        };
        auto step = [&](int j, uint xr) {
            const float ev = __uint_as_float((uint)__builtin_amdgcn_readlane(my, j));
            const float xv = __uint_as_float(xr << 16);
            acc += fmaxf(fmaf(ev, w128l, basel) + xv, 0.f);
        };

        if (cn > 0) ld(0, x0);
        if (cn > 1) ld(1, x1);
        if (cn > 2) ld(2, x2);
        if (cn > 3) ld(3, x3);
        if (cn > 4) ld(4, x4);
        if (cn > 5) ld(5, x5);
        if (cn > 6) ld(6, x6);
        if (cn > 7) ld(7, x7);

        int i = 0;
        while (i + 16 <= cn) {
            step(i + 0, x0); ld(i + 8,  x0);
            step(i + 1, x1); ld(i + 9,  x1);
            step(i + 2, x2); ld(i + 10, x2);
            step(i + 3, x3); ld(i + 11, x3);
            step(i + 4, x4); ld(i + 12, x4);
            step(i + 5, x5); ld(i + 13, x5);
            step(i + 6, x6); ld(i + 14, x6);
            step(i + 7, x7); ld(i + 15, x7);
            i += 8;
        }
        const int r = cn - i;   // 0..15
        if (r > 0)  { step(i + 0, x0); }  if (r > 8)  { ld(i + 8,  x0); }
        if (r > 1)  { step(i + 1, x1); }  if (r > 9)  { ld(i + 9,  x1); }
        if (r > 2)  { step(i + 2, x2); }  if (r > 10) { ld(i + 10, x2); }
        if (r > 3)  { step(i + 3, x3); }  if (r > 11) { ld(i + 11, x3); }
        if (r > 4)  { step(i + 4, x4); }  if (r > 12) { ld(i + 12, x4); }
        if (r > 5)  { step(i + 5, x5); }  if (r > 13) { ld(i + 13, x5); }
        if (r > 6)  { step(i + 6, x6); }  if (r > 14) { ld(i + 14, x6); }
        if (r > 7)  { step(i + 7, x7); }
        if (r > 8)  { step(i + 8,  x0); }
        if (r > 9)  { step(i + 9,  x1); }
        if (r > 10) { step(i + 10, x2); }
        if (r > 11) { step(i + 11, x3); }
        if (r > 12) { step(i + 12, x4); }
        if (r > 13) { step(i + 13, x5); }
        if (r > 14) { step(i + 14, x6); }
    }

    // fused epilogue: out[n][lane] = sum_j acc_j * W2[j][lane] + np*b2[lane]
    float o = (float)np * b2[lane];
    #pragma unroll
    for (int j = 0; j < 64; ++j) {
        const float aj = __shfl(acc, j, 64);               // v_readlane
        o = fmaf(aj, W2[(size_t)j * 64 + lane], o);        // coalesced, L1-hot
    }
    out[(size_t)n * 64 + lane] = o;
}

extern "C" void kernel_launch(void* const* d_in, const int* in_sizes, int n_in,
                              void* d_out, int out_size, void* d_ws, size_t ws_size,
                              hipStream_t stream) {
    const float* h  = (const float*)d_in[0];
    const float* e  = (const float*)d_in[1];
    const int* src  = (const int*)d_in[2];
    const int* dst  = (const int*)d_in[3];
    const float* W1 = (const float*)d_in[4];
    const float* b1 = (const float*)d_in[5];
    const float* W2 = (const float*)d_in[6];
    const float* b2 = (const float*)d_in[7];
    float* out = (float*)d_out;

    const int n_edges = in_sizes[2];
    const int N = in_sizes[0] / 64;

    // ws: [counts N | gcursor 8 (1 used) | offs N | rank E] ints,
    //     [meta 2E] ints, [abf 64N ushort], [bsf 64N ushort]
    int* counts  = (int*)d_ws;
    int* gcursor = counts + N;
    int* offs    = gcursor + 8;
    int* rank    = offs + N;
    int2* meta   = (int2*)(rank + n_edges);
    unsigned short* abf = (unsigned short*)(meta + n_edges);
    unsigned short* bsf = abf + (size_t)64 * N;

    // zero counts + cursor every call
    hipMemsetAsync(counts, 0, ((size_t)N + 8) * sizeof(int), stream);

    const int eb = (n_edges + 255) / 256;
    const int nb = (N + 255) / 256;
    const int pg = (N + NPB - 1) / NPB;

    pre_count_kernel<<<pg + eb, 256, 0, stream>>>(h, W1, b1, abf, bsf, N,
                                                  dst, counts, rank, n_edges, pg);
    alloc_offs_kernel<<<nb, 256, 0, stream>>>(counts, gcursor, offs, N);
    fill_kernel<<<eb, 256, 0, stream>>>(dst, src, e, offs, rank, meta, n_edges);
    node_accum_kernel<<<(N + 3) / 4, 256, 0, stream>>>(abf, bsf, W1, W2, b2,
                                                       offs, counts, meta, out, N);
}